// Round 1
// baseline (274.679 us; speedup 1.0000x reference)
//
#include <hip/hip_runtime.h>
#include <math.h>

// Fused AntiAliasActivation: up2 (12-tap polyphase) -> snake -> down2 (12-tap)
// x: (B=16, C=512, T=4096) fp32, out: same shape.
//
// Derived from reference (XLA conv = cross-correlation, up filter pre-flipped):
//   even t=2s:  y[t] = 2 * sum_{j=0..5} x[clamp(s-3+j)] * up[11-2j]
//   odd  t=2s+1:y[t] = 2 * sum_{j=0..5} x[clamp(s-2+j)] * up[10-2j]
//   yact = y + (1/(exp(beta)+1e-9)) * sin(y*exp(alpha))^2
//   out[o] = sum_{k=0..11} yact[clamp(2o-5+k, 0, 2T-1)] * down[k]

#define T_LEN     4096
#define TILE      1024               // outputs per block
#define NTHREADS  256
#define BPR       (T_LEN / TILE)     // blocks per row = 4
#define XTILE     (TILE + 10)        // x halo: local x indices 0..TILE+9
#define YTILE     (2 * TILE + 10)    // yact local indices 0..2*TILE+9

__global__ __launch_bounds__(NTHREADS) void aa_act_kernel(
    const float* __restrict__ x,
    const float* __restrict__ alpha,
    const float* __restrict__ beta,
    const float* __restrict__ upf,
    const float* __restrict__ downf,
    float* __restrict__ out,
    int C)
{
    __shared__ float sx[XTILE];
    __shared__ float sy[YTILE];

    const int tid  = threadIdx.x;
    const int blk  = blockIdx.x;
    const int row  = blk >> 2;          // BPR = 4
    const int o0   = (blk & (BPR - 1)) * TILE;
    const int c    = row % C;

    const float* __restrict__ xr = x + (size_t)row * T_LEN;
    float* __restrict__ outr = out + (size_t)row * T_LEN;

    // Filters to (uniform) registers
    float u[12], d[12];
#pragma unroll
    for (int i = 0; i < 12; ++i) { u[i] = upf[i]; d[i] = downf[i]; }

    const float ea = __expf(alpha[c]);
    const float rb = 1.0f / (__expf(beta[c]) + 1e-9f);

    // Stage 1: x tile + halo into LDS, edge-clamped (handles jnp.pad edge mode)
    for (int i = tid; i < XTILE; i += NTHREADS) {
        int g = o0 - 5 + i;
        g = min(max(g, 0), T_LEN - 1);
        sx[i] = xr[g];
    }
    __syncthreads();

    // Stage 2: upsample (2-phase) + snake activation into LDS
    for (int i = tid; i < YTILE; i += NTHREADS) {
        int t = 2 * o0 - 5 + i;
        t = min(max(t, 0), 2 * T_LEN - 1);   // edge clamp of the down-conv pad
        int s = t >> 1;
        float y;
        if ((t & 1) == 0) {
            int bl = s + 2 - o0;             // global x base s-3, local = +5 halo
            y = sx[bl]     * u[11] + sx[bl + 1] * u[9] + sx[bl + 2] * u[7]
              + sx[bl + 3] * u[5]  + sx[bl + 4] * u[3] + sx[bl + 5] * u[1];
        } else {
            int bl = s + 3 - o0;             // global x base s-2
            y = sx[bl]     * u[10] + sx[bl + 1] * u[8] + sx[bl + 2] * u[6]
              + sx[bl + 3] * u[4]  + sx[bl + 4] * u[2] + sx[bl + 5] * u[0];
        }
        y *= 2.0f;
        float sv = __sinf(y * ea);
        sy[i] = y + rb * sv * sv;
    }
    __syncthreads();

    // Stage 3: 12-tap downsample, stride 2; coalesced stores
#pragma unroll
    for (int i = 0; i < TILE / NTHREADS; ++i) {
        int lo = i * NTHREADS + tid;
        int base = 2 * lo;                   // sy index of tap k=0
        float acc = 0.0f;
#pragma unroll
        for (int k = 0; k < 12; ++k) acc += sy[base + k] * d[k];
        outr[o0 + lo] = acc;
    }
}

extern "C" void kernel_launch(void* const* d_in, const int* in_sizes, int n_in,
                              void* d_out, int out_size, void* d_ws, size_t ws_size,
                              hipStream_t stream) {
    const float* x     = (const float*)d_in[0];
    const float* alpha = (const float*)d_in[1];
    const float* beta  = (const float*)d_in[2];
    const float* upf   = (const float*)d_in[3];
    const float* downf = (const float*)d_in[4];
    float* out = (float*)d_out;

    const int C    = in_sizes[1];            // 512
    const int rows = in_sizes[0] / T_LEN;    // B*C = 8192

    dim3 grid(rows * BPR), block(NTHREADS);
    hipLaunchKernelGGL(aa_act_kernel, grid, block, 0, stream,
                       x, alpha, beta, upf, downf, out, C);
}

// Round 2
// 268.222 us; speedup vs baseline: 1.0241x; 1.0241x over previous
//
#include <hip/hip_runtime.h>
#include <math.h>

// Fused AntiAliasActivation: up2 (12-tap polyphase) -> snake -> down2 (12-tap)
// x: (B=16, C=512, T=4096) fp32, out: same shape.
//
//   even t=2s:  y[t] = 2 * sum_{j=0..5} x[clamp(s-3+j)] * up[11-2j]
//   odd  t=2s+1:y[t] = 2 * sum_{j=0..5} x[clamp(s-2+j)] * up[10-2j]
//   yact = y + (1/(exp(beta)+1e-9)) * sin(y*exp(alpha))^2
//   out[o] = sum_{k=0..11} yact[clamp(2o-5+k, 0, 2T-1)] * down[k]
//
// R2 restructure vs R1 (117us, VALUBusy 91% -> VALU-bound):
//  - stage2: thread computes an even/odd PAIR -> no wave divergence, both
//    phases share the same 6 sx values (6 ds_read per 2 yact, was 12 + 2x ALU)
//  - edge t-clamp hoisted out of the hot loop: 5-entry fixup in edge blocks only
//  - stage3: 4 outputs/thread, sy read as 5x ds_read_b128, dwordx4 store

#define T_LEN     4096
#define TILE      1024                // outputs per block
#define NT        256
#define BPR       (T_LEN / TILE)      // 4 blocks per row
#define XT        (TILE + 12)         // sx[j] = x[clamp(o0-5+j)]
#define PAIRS     (TILE + 6)          // pair p covers yact local i = 2p, 2p+1
#define YT        (2 * TILE + 12)     // = 2060 floats, 515 float4s exactly

__device__ __forceinline__ float yact_gen(const float* sx, int o0, int i,
                                          float ea, float rb, const float* u) {
    int t = 2 * o0 - 5 + i;
    t = min(max(t, 0), 2 * T_LEN - 1);
    int s = t >> 1;
    float y = 0.0f;
    if ((t & 1) == 0) {
        int gb = s - 3;
#pragma unroll
        for (int m = 0; m < 6; ++m) {
            int g = min(max(gb + m, 0), T_LEN - 1);
            y = fmaf(sx[g - o0 + 5], u[11 - 2 * m], y);
        }
    } else {
        int gb = s - 2;
#pragma unroll
        for (int m = 0; m < 6; ++m) {
            int g = min(max(gb + m, 0), T_LEN - 1);
            y = fmaf(sx[g - o0 + 5], u[10 - 2 * m], y);
        }
    }
    y *= 2.0f;
    float sv = __sinf(y * ea);
    return fmaf(rb * sv, sv, y);
}

__global__ __launch_bounds__(NT) void aa_act_kernel(
    const float* __restrict__ x,
    const float* __restrict__ alpha,
    const float* __restrict__ beta,
    const float* __restrict__ upf,
    const float* __restrict__ downf,
    float* __restrict__ out,
    int C)
{
    __shared__ __align__(16) float sx[XT];
    __shared__ __align__(16) float sy[YT];

    const int tid = threadIdx.x;
    const int blk = blockIdx.x;
    const int row = blk >> 2;               // BPR = 4
    const int o0  = (blk & (BPR - 1)) * TILE;
    const int c   = row % C;

    const float* __restrict__ xr = x + (size_t)row * T_LEN;
    float* __restrict__ outr = out + (size_t)row * T_LEN;

    float u[12], d[12];
#pragma unroll
    for (int i = 0; i < 12; ++i) { u[i] = upf[i]; d[i] = downf[i]; }

    const float ea = __expf(alpha[c]);
    const float rb = 1.0f / (__expf(beta[c]) + 1e-9f);

    // ---- Stage 1: x tile + halo into LDS, edge-clamped ----
    for (int j = tid; j < XT; j += NT) {
        int g = o0 - 5 + j;
        g = min(max(g, 0), T_LEN - 1);
        sx[j] = xr[g];
    }
    __syncthreads();

    // ---- Stage 2: phase-pair upsample + snake, no divergence ----
    // pair p: i0 = 2p  -> t0 = 2*o0-5+2p (ODD phase,  s = o0-3+p, taps u[10..0 even])
    //         i1 = 2p+1-> t1 = t0+1      (EVEN phase, s = o0-2+p, taps u[11..1 odd])
    // both read sx[p .. p+5]
    for (int p = tid; p < PAIRS; p += NT) {
        float x0 = sx[p],     x1 = sx[p + 1], x2 = sx[p + 2];
        float x3 = sx[p + 3], x4 = sx[p + 4], x5 = sx[p + 5];
        float yo = x0 * u[10];
        yo = fmaf(x1, u[8], yo); yo = fmaf(x2, u[6], yo);
        yo = fmaf(x3, u[4], yo); yo = fmaf(x4, u[2], yo);
        yo = fmaf(x5, u[0], yo);
        float ye = x0 * u[11];
        ye = fmaf(x1, u[9], ye); ye = fmaf(x2, u[7], ye);
        ye = fmaf(x3, u[5], ye); ye = fmaf(x4, u[3], ye);
        ye = fmaf(x5, u[1], ye);
        yo *= 2.0f; ye *= 2.0f;
        float so = __sinf(yo * ea);
        float se = __sinf(ye * ea);
        float2 pr;
        pr.x = fmaf(rb * so, so, yo);
        pr.y = fmaf(rb * se, se, ye);
        *(float2*)(sy + 2 * p) = pr;
    }
    __syncthreads();

    // ---- Edge fix-up: t-clamp only matters for <=5 entries per tensor edge ----
    if (o0 == 0 && tid < 5) {
        sy[tid] = yact_gen(sx, o0, tid, ea, rb, u);                 // i = 0..4
    }
    if (o0 + TILE >= T_LEN && tid < 5) {
        int i = 2 * TILE + 5 + tid;                                 // i = 2T+5..2T+9
        sy[i] = yact_gen(sx, o0, i, ea, rb, u);
    }
    __syncthreads();

    // ---- Stage 3: 4 outputs/thread, vector LDS reads, dwordx4 store ----
    const float4* sy4 = (const float4*)sy;
    float w[20];
#pragma unroll
    for (int q = 0; q < 5; ++q) {
        float4 v = sy4[2 * tid + q];
        w[4 * q + 0] = v.x; w[4 * q + 1] = v.y;
        w[4 * q + 2] = v.z; w[4 * q + 3] = v.w;
    }
    float a0 = 0.f, a1 = 0.f, a2 = 0.f, a3 = 0.f;
#pragma unroll
    for (int k = 0; k < 12; ++k) {
        a0 = fmaf(d[k], w[k],     a0);
        a1 = fmaf(d[k], w[k + 2], a1);
        a2 = fmaf(d[k], w[k + 4], a2);
        a3 = fmaf(d[k], w[k + 6], a3);
    }
    float4 o4; o4.x = a0; o4.y = a1; o4.z = a2; o4.w = a3;
    ((float4*)(outr + o0))[tid] = o4;
}

extern "C" void kernel_launch(void* const* d_in, const int* in_sizes, int n_in,
                              void* d_out, int out_size, void* d_ws, size_t ws_size,
                              hipStream_t stream) {
    const float* x     = (const float*)d_in[0];
    const float* alpha = (const float*)d_in[1];
    const float* beta  = (const float*)d_in[2];
    const float* upf   = (const float*)d_in[3];
    const float* downf = (const float*)d_in[4];
    float* out = (float*)d_out;

    const int C    = in_sizes[1];             // 512
    const int rows = in_sizes[0] / T_LEN;     // B*C = 8192

    dim3 grid(rows * BPR), block(NT);
    hipLaunchKernelGGL(aa_act_kernel, grid, block, 0, stream,
                       x, alpha, beta, upf, downf, out, C);
}

// Round 3
// 242.247 us; speedup vs baseline: 1.1339x; 1.1072x over previous
//
#include <hip/hip_runtime.h>
#include <math.h>

// Fused AntiAliasActivation: up2 (12-tap polyphase) -> snake -> down2 (12-tap)
// x: (B=16, C=512, T=4096) fp32, out: same shape.
//
// Phase-plane formulation (R3):
//   E[s] = yact[2s]   = act( 2*sum_m x[clamp(s-3+m)]*u[11-2m] )
//   O[s] = yact[2s+1] = act( 2*sum_m x[clamp(s-2+m)]*u[10-2m] )
//   out[o] = sum_m E[o-2+m]*d[2m+1] + sum_m O[o-3+m]*d[2m]
//   act(y) = y + rb*sin(y*ea)^2
// Down-conv edge clamp (t<0 -> yact[0]=E[0]; t>2T-1 -> yact[2T-1]=O[T-1])
// handled by a tiny fixup pass in the two edge blocks per row.
//
// R3 vs R2 (111us, 2.46e7 LDS bank conflicts from stride-2 b128 reads):
// de-interleaved planes make EVERY LDS access stride-1 float4 (b128,
// conflict-free); stage1/2/3 fully vectorized 16B reads+writes.

#define T_LEN 4096
#define TILE  1024               // outputs per block
#define NT    256
#define BPR   (T_LEN / TILE)     // 4
#define XT4   260                // sx float4 count: sx[i] = x[clamp(o0-8+i)], i<1040
#define NG    258                // stage-2 groups of 4 (plane idx j = 0..1031)
#define PL4   260                // sE/sO float4 count (1040 floats, 1032 used)

__global__ __launch_bounds__(NT) void aa_act_kernel(
    const float* __restrict__ x,
    const float* __restrict__ alpha,
    const float* __restrict__ beta,
    const float* __restrict__ upf,
    const float* __restrict__ downf,
    float* __restrict__ out,
    int C)
{
    __shared__ __align__(16) float sx[XT4 * 4];
    __shared__ __align__(16) float sE[PL4 * 4];   // sE[j] = E[o0-2+j]
    __shared__ __align__(16) float sO[PL4 * 4];   // sO[j] = O[o0-3+j]

    const int tid = threadIdx.x;
    const int blk = blockIdx.x;
    const int row = blk >> 2;                 // BPR = 4
    const int o0  = (blk & (BPR - 1)) * TILE;
    const int c   = row % C;

    const float* __restrict__ xr = x + (size_t)row * T_LEN;
    float* __restrict__ outr = out + (size_t)row * T_LEN;

    float u[12], d[12];
#pragma unroll
    for (int i = 0; i < 12; ++i) { u[i] = upf[i]; d[i] = downf[i]; }

    const float ea = __expf(alpha[c]);
    const float rb = 1.0f / (__expf(beta[c]) + 1e-9f);

    // ---- Stage 1: x tile (+8 halo each side) into LDS as float4 ----
    const bool eblk = (o0 == 0) || (o0 + TILE == T_LEN);
    for (int i4 = tid; i4 < XT4; i4 += NT) {
        int gi = o0 - 8 + 4 * i4;
        float4 v;
        if (!eblk || (unsigned)gi <= (unsigned)(T_LEN - 4)) {
            v = *(const float4*)(xr + gi);
        } else {
            v.x = xr[min(max(gi + 0, 0), T_LEN - 1)];
            v.y = xr[min(max(gi + 1, 0), T_LEN - 1)];
            v.z = xr[min(max(gi + 2, 0), T_LEN - 1)];
            v.w = xr[min(max(gi + 3, 0), T_LEN - 1)];
        }
        ((float4*)sx)[i4] = v;
    }
    __syncthreads();

    // ---- Stage 2: 4 phase-pairs per thread; all-b128, stride-1 ----
    // pair j: s = o0-3+j; window x[s-2..s+3] = sx[j+3 .. j+8]
    //   sO[j] = act(2*sum f[.]*u[10-2m]);  sE[j] = act(2*sum f[.]*u[11-2m])
    const float4* sx4 = (const float4*)sx;
    for (int g = tid; g < NG; g += NT) {
        float4 A = sx4[g], Bv = sx4[g + 1], Cv = sx4[g + 2];
        float f[12] = { A.x, A.y, A.z, A.w, Bv.x, Bv.y, Bv.z, Bv.w,
                        Cv.x, Cv.y, Cv.z, Cv.w };
        float eo[4], oo[4];
#pragma unroll
        for (int r = 0; r < 4; ++r) {
            float yo = f[r + 3] * u[10];
            yo = fmaf(f[r + 4], u[8], yo);
            yo = fmaf(f[r + 5], u[6], yo);
            yo = fmaf(f[r + 6], u[4], yo);
            yo = fmaf(f[r + 7], u[2], yo);
            yo = fmaf(f[r + 8], u[0], yo);
            float ye = f[r + 3] * u[11];
            ye = fmaf(f[r + 4], u[9], ye);
            ye = fmaf(f[r + 5], u[7], ye);
            ye = fmaf(f[r + 6], u[5], ye);
            ye = fmaf(f[r + 7], u[3], ye);
            ye = fmaf(f[r + 8], u[1], ye);
            yo *= 2.0f; ye *= 2.0f;
            float so_ = __sinf(yo * ea);
            float se_ = __sinf(ye * ea);
            oo[r] = fmaf(rb * so_, so_, yo);
            eo[r] = fmaf(rb * se_, se_, ye);
        }
        float4 ev; ev.x = eo[0]; ev.y = eo[1]; ev.z = eo[2]; ev.w = eo[3];
        float4 ov; ov.x = oo[0]; ov.y = oo[1]; ov.z = oo[2]; ov.w = oo[3];
        ((float4*)sE)[g] = ev;
        ((float4*)sO)[g] = ov;
    }
    __syncthreads();

    // ---- Edge fixup: down-conv pad clamp (first/last block only) ----
    if (o0 == 0) {
        float L = sE[2];                       // E[0]
        if (tid < 2) sE[tid] = L;              // E[-2],E[-1] -> E[0]
        if (tid < 3) sO[tid] = L;              // O[-3..-1] -> yact[0]=E[0]
    }
    if (o0 + TILE == T_LEN) {
        float R = sO[TILE + 2];                // O[T-1]
        if (tid < 6) sE[TILE + 2 + tid] = R;   // E[s>=T] -> yact[2T-1]
        if (tid < 5) sO[TILE + 3 + tid] = R;   // O[s>=T] -> yact[2T-1]
    }
    __syncthreads();

    // ---- Stage 3: dual 6-tap stride-1 conv; 4 outputs/thread ----
    const float4* e4 = (const float4*)sE;
    const float4* q4 = (const float4*)sO;
    float4 E0 = e4[tid], E1 = e4[tid + 1], E2 = e4[tid + 2];
    float4 O0 = q4[tid], O1 = q4[tid + 1], O2 = q4[tid + 2];
    float e[12] = { E0.x, E0.y, E0.z, E0.w, E1.x, E1.y, E1.z, E1.w,
                    E2.x, E2.y, E2.z, E2.w };
    float o_[12] = { O0.x, O0.y, O0.z, O0.w, O1.x, O1.y, O1.z, O1.w,
                     O2.x, O2.y, O2.z, O2.w };
    float acc[4];
#pragma unroll
    for (int r = 0; r < 4; ++r) {
        float a = e[r] * d[1];
        a = fmaf(e[r + 1], d[3],  a);
        a = fmaf(e[r + 2], d[5],  a);
        a = fmaf(e[r + 3], d[7],  a);
        a = fmaf(e[r + 4], d[9],  a);
        a = fmaf(e[r + 5], d[11], a);
        a = fmaf(o_[r],     d[0],  a);
        a = fmaf(o_[r + 1], d[2],  a);
        a = fmaf(o_[r + 2], d[4],  a);
        a = fmaf(o_[r + 3], d[6],  a);
        a = fmaf(o_[r + 4], d[8],  a);
        a = fmaf(o_[r + 5], d[10], a);
        acc[r] = a;
    }
    float4 o4; o4.x = acc[0]; o4.y = acc[1]; o4.z = acc[2]; o4.w = acc[3];
    ((float4*)(outr + o0))[tid] = o4;
}

extern "C" void kernel_launch(void* const* d_in, const int* in_sizes, int n_in,
                              void* d_out, int out_size, void* d_ws, size_t ws_size,
                              hipStream_t stream) {
    const float* x     = (const float*)d_in[0];
    const float* alpha = (const float*)d_in[1];
    const float* beta  = (const float*)d_in[2];
    const float* upf   = (const float*)d_in[3];
    const float* downf = (const float*)d_in[4];
    float* out = (float*)d_out;

    const int C    = in_sizes[1];             // 512
    const int rows = in_sizes[0] / T_LEN;     // B*C = 8192

    dim3 grid(rows * BPR), block(NT);
    hipLaunchKernelGGL(aa_act_kernel, grid, block, 0, stream,
                       x, alpha, beta, upf, downf, out, C);
}